// Round 2
// baseline (1047.829 us; speedup 1.0000x reference)
//
#include <hip/hip_runtime.h>
#include <math.h>

typedef __bf16 bf16;
typedef bf16 bf16x8 __attribute__((ext_vector_type(8)));
typedef bf16 bf16x4 __attribute__((ext_vector_type(4)));
typedef float f32x4 __attribute__((ext_vector_type(4)));

// ---------------- workspace layout (byte offsets) ----------------
#define OFF_GLOB   0ul          // 4*32*1024 f32      = 524288
#define OFF_H      524288ul     // 8*32*256 f32       = 262144
#define OFF_SCORE  786432ul     // 8*32 f32           = 1024
#define OFF_COND   787456ul     // 8 f32 (+pad)       = 1024
#define OFF_ZP     788480ul     // zero page          = 4096
#define OFF_PART   792576ul     // 4*8*32*1024 f32    = 4194304
#define OFF_PROJ   4986880ul    // 2*128*32*1024 bf16 = 16777216
#define OFF_WTF2S  21764096ul   // 2*5120*1024 bf16   = 20971520
#define OFF_WTS2F  42735616ul   // 1024*1024 bf16     = 2097152
// total = 44832768 (~43 MB, under the known-good 62 MB)

// out layout: out0 @0 (512*32*1024), out1 @16777216, out2 @33554432, out3 @37748736

// async global->LDS, 16B per lane. LDS dst must be wave-uniform base + lane*16.
__device__ __forceinline__ void gll16(const void* gsrc, void* ldst) {
  __builtin_amdgcn_global_load_lds(
      (const __attribute__((address_space(1))) unsigned int*)gsrc,
      (__attribute__((address_space(3))) unsigned int*)ldst, 16, 0, 0);
}

// slot 0..3: slow->fast (2,0)(3,0)(2,1)(3,1) ; slot 4..7: fast->slow (0,2)(1,2)(0,3)(1,3)
__device__ __forceinline__ void slot_ij(int s, int& i, int& j) {
  if (s < 4) { i = 2 + (s & 1); j = s >> 1; }
  else       { int ss = s - 4; i = ss & 1; j = 2 + (ss >> 1); }
}

// ---------------- means ----------------
__global__ __launch_bounds__(256) void k_means_part(
    const float* __restrict__ f0, const float* __restrict__ f1,
    const float* __restrict__ f2, const float* __restrict__ f3,
    float* __restrict__ part)
{
  int b = blockIdx.x, c = blockIdx.y, i = blockIdx.z, tid = threadIdx.x;
  const float* f = (i == 0) ? f0 : (i == 1) ? f1 : (i == 2) ? f2 : f3;
  int chunk = (i < 2) ? 64 : 16;
  int t0 = c * chunk;
  float4 s = make_float4(0.f, 0.f, 0.f, 0.f);
  for (int t = t0; t < t0 + chunk; ++t) {
    float4 v = ((const float4*)(f + (size_t)(t * 32 + b) * 1024))[tid];
    s.x += v.x; s.y += v.y; s.z += v.z; s.w += v.w;
  }
  ((float4*)part)[(size_t)((i * 8 + c) * 32 + b) * 256 + tid] = s;
}

__global__ __launch_bounds__(256) void k_means_final(
    const float* __restrict__ part, float* __restrict__ g)
{
  int b = blockIdx.x, i = blockIdx.y, tid = threadIdx.x;
  float4 s = make_float4(0.f, 0.f, 0.f, 0.f);
  for (int c = 0; c < 8; ++c) {
    float4 v = ((const float4*)part)[(size_t)((i * 8 + c) * 32 + b) * 256 + tid];
    s.x += v.x; s.y += v.y; s.z += v.z; s.w += v.w;
  }
  float inv = (i < 2) ? (1.f / 512.f) : (1.f / 128.f);
  s.x *= inv; s.y *= inv; s.z *= inv; s.w *= inv;
  ((float4*)g)[(size_t)(i * 32 + b) * 256 + tid] = s;
}

// ---------------- MLP layer 1 ----------------
__global__ __launch_bounds__(256) void k_mlp1(
    const float* __restrict__ g, const float* __restrict__ w1, float* __restrict__ h_ws)
{
  int s = blockIdx.x, hc = blockIdx.y, kz = blockIdx.z, tid = threadIdx.x;
  int pi, pj; slot_ij(s, pi, pj);
  int p = pi * 4 + pj;
  int h = hc * 32 + (tid & 31);
  int bg = tid >> 5;
  __shared__ float pv[32 * 65];
  float acc0 = 0.f, acc1 = 0.f, acc2 = 0.f, acc3 = 0.f;
  for (int kt = 0; kt < 8; ++kt) {
    int k0 = kz * 512 + kt * 64;
    __syncthreads();
    for (int l = tid; l < 2048; l += 256) {
      int bb = l >> 6, kk = l & 63;
      int k = k0 + kk;
      float v = (k < 1024) ? g[(size_t)pi * 32768 + bb * 1024 + k]
                           : g[(size_t)pj * 32768 + bb * 1024 + (k - 1024)];
      pv[bb * 65 + kk] = v;
    }
    __syncthreads();
    const float* wp = w1 + ((size_t)p * 2048 + k0) * 256 + hc * 32 + (tid & 31);
    for (int kk = 0; kk < 64; ++kk) {
      float w = wp[(size_t)kk * 256];
      acc0 += pv[(bg * 4 + 0) * 65 + kk] * w;
      acc1 += pv[(bg * 4 + 1) * 65 + kk] * w;
      acc2 += pv[(bg * 4 + 2) * 65 + kk] * w;
      acc3 += pv[(bg * 4 + 3) * 65 + kk] * w;
    }
  }
  atomicAdd(&h_ws[(size_t)s * 8192 + (bg * 4 + 0) * 256 + h], acc0);
  atomicAdd(&h_ws[(size_t)s * 8192 + (bg * 4 + 1) * 256 + h], acc1);
  atomicAdd(&h_ws[(size_t)s * 8192 + (bg * 4 + 2) * 256 + h], acc2);
  atomicAdd(&h_ws[(size_t)s * 8192 + (bg * 4 + 3) * 256 + h], acc3);
}

// ---------------- MLP layer 2 + sigmoid + mean + cond ----------------
__global__ __launch_bounds__(256) void k_mlp2(
    const float* __restrict__ h_ws, const float* __restrict__ b1,
    const float* __restrict__ w2, const float* __restrict__ b2,
    float* __restrict__ score, float* __restrict__ cond)
{
  int s = blockIdx.x, tid = threadIdx.x;
  int pi, pj; slot_ij(s, pi, pj);
  int p = pi * 4 + pj;
  float w2v = w2[p * 256 + tid];
  float b1v = b1[p * 256 + tid];
  float b2v = b2[p];
  __shared__ float red[4];
  float tot = 0.f;
  for (int b = 0; b < 32; ++b) {
    float v = fmaxf(h_ws[(size_t)s * 8192 + b * 256 + tid] + b1v, 0.f) * w2v;
    for (int off = 32; off > 0; off >>= 1) v += __shfl_down(v, off);
    if ((tid & 63) == 0) red[tid >> 6] = v;
    __syncthreads();
    if (tid == 0) {
      float sum = red[0] + red[1] + red[2] + red[3] + b2v;
      float sc = 1.f / (1.f + expf(-sum));
      score[s * 32 + b] = sc;
      tot += sc;
    }
    __syncthreads();
  }
  if (tid == 0) cond[s] = (tot * (1.f / 32.f) >= 0.3f) ? 1.f : 0.f;
}

// ---------------- f2s weight transpose -> B^T [co][kappa=kk*1024+ci] bf16 ----------------
__global__ __launch_bounds__(256) void k_f2s_transpose(
    const float* __restrict__ w, const float* __restrict__ cond, bf16* __restrict__ wT)
{
  int z = blockIdx.y, co = blockIdx.x, tid = threadIdx.x;
  int sel = (cond[5 + 2 * z] > 0.5f) ? 1 : ((cond[4 + 2 * z] > 0.5f) ? 0 : -1);
  if (sel < 0) return;
  int widx = sel * 2 + z;
  __shared__ float buf[5120];
  const float* src = w + ((size_t)widx * 1024 + co) * 5120;
  for (int l = tid; l < 5120; l += 256) buf[l] = src[l];
  __syncthreads();
  bf16* dst = wT + (size_t)z * 5242880 + (size_t)co * 5120;
  for (int o = tid; o < 5120; o += 256) {
    int kk = o >> 10, ci = o & 1023;
    dst[o] = (bf16)buf[ci * 5 + kk];
  }
}

// ---------------- s2f weight convert ----------------
__global__ __launch_bounds__(256) void k_s2f_convert(
    const float* __restrict__ w, bf16* __restrict__ wT)
{
  size_t gi = (size_t)blockIdx.x * 256 + threadIdx.x;
  float4 v = ((const float4*)w)[gi];
  bf16x4 o;
  o[0] = (bf16)v.x; o[1] = (bf16)v.y; o[2] = (bf16)v.z; o[3] = (bf16)v.w;
  *(bf16x4*)&wT[gi * 4] = o;
}

// ---------------- unified GEMM kernel ----------------
// z=0,1: f2s (K=5120 im2col, epilogue residual -> out2/3)
// z=2,3: s2f (K=1024 1x1 conv, epilogue -> proj bf16)
// tile 64x128, BK=64, 4 waves each 32x64 (2x4 frags)
#define MFMA_COMPUTE()                                                                       \
  do {                                                                                       \
    _Pragma("unroll") for (int ks = 0; ks < 2; ++ks) {                                       \
      bf16x8 af[2]; bf16x8 bfv[4];                                                           \
      _Pragma("unroll") for (int mi = 0; mi < 2; ++mi) {                                     \
        const float* ap = &As[(wr + mi * 16 + rl) * 64 + ks * 32 + q * 8];                   \
        float4 a0 = *(const float4*)ap; float4 a1 = *(const float4*)(ap + 4);                \
        bf16x8 t8;                                                                           \
        t8[0] = (bf16)a0.x; t8[1] = (bf16)a0.y; t8[2] = (bf16)a0.z; t8[3] = (bf16)a0.w;      \
        t8[4] = (bf16)a1.x; t8[5] = (bf16)a1.y; t8[6] = (bf16)a1.z; t8[7] = (bf16)a1.w;      \
        af[mi] = t8;                                                                         \
      }                                                                                      \
      _Pragma("unroll") for (int ni = 0; ni < 4; ++ni)                                       \
        bfv[ni] = *(const bf16x8*)&Bs[(wc + ni * 16 + rl) * 64 + ks * 32 + q * 8];           \
      _Pragma("unroll") for (int mi = 0; mi < 2; ++mi)                                       \
        _Pragma("unroll") for (int ni = 0; ni < 4; ++ni)                                     \
          acc[mi][ni] = __builtin_amdgcn_mfma_f32_16x16x32_bf16(af[mi], bfv[ni],             \
                                                                acc[mi][ni], 0, 0, 0);       \
    }                                                                                        \
  } while (0)

__global__ __launch_bounds__(256) void k_gemms(
    const float* __restrict__ f0, const float* __restrict__ f1,
    const float* __restrict__ f2, const float* __restrict__ f3,
    const bf16* __restrict__ wtf, const bf16* __restrict__ wts,
    const float* __restrict__ s2fb, const float* __restrict__ score,
    const float* __restrict__ cond, const float* __restrict__ zp,
    bf16* __restrict__ proj, float* __restrict__ out)
{
  __shared__ float As[64 * 64];   // 16 KB
  __shared__ bf16 Bs[128 * 64];   // 16 KB
  __shared__ float sld[32];
  int tid = threadIdx.x;
  int bz = blockIdx.z;
  int M0 = blockIdx.x * 64, N0 = blockIdx.y * 128;
  int lane = tid & 63, wv = tid >> 6;
  int wr = (wv >> 1) * 32, wc = (wv & 1) * 64;
  int rl = lane & 15, q = lane >> 4;
  f32x4 acc[2][4];
  #pragma unroll
  for (int a = 0; a < 2; ++a)
    #pragma unroll
    for (int c = 0; c < 4; ++c) { acc[a][c][0] = 0.f; acc[a][c][1] = 0.f; acc[a][c][2] = 0.f; acc[a][c][3] = 0.f; }

  if (bz < 2) {
    // ---------- fast -> slow ----------
    int z = bz;
    const float* fj = z ? f3 : f2;
    float* oj = out + 33554432ul + (size_t)z * 4194304;
    int sel = (cond[5 + 2 * z] > 0.5f) ? 1 : ((cond[4 + 2 * z] > 0.5f) ? 0 : -1);
    if (sel < 0) {  // passthrough this 64x128 slice
      for (int l = tid; l < 2048; l += 256) {
        int rr = l >> 5, c = (l & 31) * 4;
        size_t idx = (size_t)(M0 + rr) * 1024 + N0 + c;
        *(float4*)(oj + idx) = *(const float4*)(fj + idx);
      }
      return;
    }
    const float* A = sel ? f1 : f0;
    const bf16* wB = wtf + (size_t)z * 5242880;
    if (tid < 32) sld[tid] = score[((sel ? 5 : 4) + 2 * z) * 32 + tid];
    for (int kt = 0; kt < 80; ++kt) {
      int kk = kt >> 4, ci0 = (kt & 15) << 6;
      // stage A (f32, im2col rows; OOB rows redirected to zero page)
      #pragma unroll
      for (int u = 0; u < 4; ++u) {
        int m = u * 16 + (tid >> 4);
        int gc = (tid & 15) * 4;
        int mm = M0 + m, t = mm >> 5, b = mm & 31;
        int pos = 4 * t - 2 + kk;
        const float* ga = (pos >= 0)
            ? A + (((size_t)(pos * 32 + b)) << 10) + ci0 + gc
            : zp + gc;
        gll16(ga, &As[m * 64 + gc]);
      }
      // stage B (bf16 wT)
      #pragma unroll
      for (int u = 0; u < 4; ++u) {
        int n = u * 32 + (tid >> 3);
        int gc = (tid & 7) * 8;
        gll16(wB + (size_t)(N0 + n) * 5120 + kt * 64 + gc, &Bs[n * 64 + gc]);
      }
      __syncthreads();
      MFMA_COMPUTE();
      __syncthreads();
    }
    #pragma unroll
    for (int mi = 0; mi < 2; ++mi)
      #pragma unroll
      for (int ni = 0; ni < 4; ++ni) {
        int gm = M0 + wr + mi * 16 + q * 4;
        int gn = N0 + wc + ni * 16 + rl;
        #pragma unroll
        for (int r = 0; r < 4; ++r) {
          size_t idx = (size_t)(gm + r) * 1024 + gn;
          oj[idx] = fj[idx] + sld[(gm + r) & 31] * acc[mi][ni][r];
        }
      }
  } else {
    // ---------- slow -> fast projection (1x1 conv) ----------
    int z = bz - 2;
    int sel = (cond[1 + 2 * z] > 0.5f) ? 3 : ((cond[2 * z] > 0.5f) ? 2 : -1);
    if (sel < 0) return;  // proj unused; interp passes through
    const float* A = (sel == 3) ? f3 : f2;
    bf16* pj = proj + (size_t)z * 4194304;
    for (int kt = 0; kt < 16; ++kt) {
      int ci0 = kt << 6;
      #pragma unroll
      for (int u = 0; u < 4; ++u) {
        int m = u * 16 + (tid >> 4);
        int gc = (tid & 15) * 4;
        gll16(A + (((size_t)(M0 + m)) << 10) + ci0 + gc, &As[m * 64 + gc]);
      }
      #pragma unroll
      for (int u = 0; u < 4; ++u) {
        int n = u * 32 + (tid >> 3);
        int gc = (tid & 7) * 8;
        gll16(wts + (size_t)(N0 + n) * 1024 + ci0 + gc, &Bs[n * 64 + gc]);
      }
      __syncthreads();
      MFMA_COMPUTE();
      __syncthreads();
    }
    #pragma unroll
    for (int mi = 0; mi < 2; ++mi)
      #pragma unroll
      for (int ni = 0; ni < 4; ++ni) {
        int gm = M0 + wr + mi * 16 + q * 4;
        int gn = N0 + wc + ni * 16 + rl;
        float bv = s2fb[gn];
        #pragma unroll
        for (int r = 0; r < 4; ++r)
          pj[(size_t)(gm + r) * 1024 + gn] = (bf16)(acc[mi][ni][r] + bv);
      }
  }
}

// ---------------- interp + residual -> out0/out1 ----------------
__global__ __launch_bounds__(256) void k_interp(
    const float* __restrict__ f0, const float* __restrict__ f1,
    const bf16* __restrict__ proj, const float* __restrict__ score,
    const float* __restrict__ cond, float* __restrict__ out)
{
  int z = blockIdx.y, tb = blockIdx.x, tid = threadIdx.x;
  const float* fj = z ? f1 : f0;
  float* oj = out + (size_t)z * 16777216;
  int sel = (cond[1 + 2 * z] > 0.5f) ? 3 : ((cond[2 * z] > 0.5f) ? 2 : -1);
  float4 fv = ((const float4*)(fj + (size_t)tb * 1024))[tid];
  if (sel < 0) {
    ((float4*)(oj + (size_t)tb * 1024))[tid] = fv;
    return;
  }
  int t = tb >> 5, b = tb & 31;
  int slot = 2 * z + (sel == 3 ? 1 : 0);
  float s = score[slot * 32 + b];
  float srcf = 0.25f * (float)t - 0.375f;
  srcf = fminf(fmaxf(srcf, 0.f), 127.f);
  int i0 = (int)srcf;
  int i1 = min(i0 + 1, 127);
  float w = srcf - (float)i0;
  const bf16* pz = proj + (size_t)z * 4194304;
  bf16x4 a4 = *(const bf16x4*)&pz[((size_t)(i0 * 32 + b)) * 1024 + tid * 4];
  bf16x4 c4 = *(const bf16x4*)&pz[((size_t)(i1 * 32 + b)) * 1024 + tid * 4];
  float4 o;
  o.x = fv.x + s * ((1.f - w) * (float)a4[0] + w * (float)c4[0]);
  o.y = fv.y + s * ((1.f - w) * (float)a4[1] + w * (float)c4[1]);
  o.z = fv.z + s * ((1.f - w) * (float)a4[2] + w * (float)c4[2]);
  o.w = fv.w + s * ((1.f - w) * (float)a4[3] + w * (float)c4[3]);
  ((float4*)(oj + (size_t)tb * 1024))[tid] = o;
}

// ---------------- launch ----------------
extern "C" void kernel_launch(void* const* d_in, const int* in_sizes, int n_in,
                              void* d_out, int out_size, void* d_ws, size_t ws_size,
                              hipStream_t stream) {
  const float* f0   = (const float*)d_in[0];
  const float* f1   = (const float*)d_in[1];
  const float* f2   = (const float*)d_in[2];
  const float* f3   = (const float*)d_in[3];
  const float* w1   = (const float*)d_in[4];
  const float* b1   = (const float*)d_in[5];
  const float* w2   = (const float*)d_in[6];
  const float* b2   = (const float*)d_in[7];
  const float* s2fw = (const float*)d_in[8];
  const float* s2fb = (const float*)d_in[9];
  const float* f2sw = (const float*)d_in[10];
  float* out = (float*)d_out;

  char* ws = (char*)d_ws;
  float* g     = (float*)(ws + OFF_GLOB);
  float* h_ws  = (float*)(ws + OFF_H);
  float* score = (float*)(ws + OFF_SCORE);
  float* cond  = (float*)(ws + OFF_COND);
  float* zp    = (float*)(ws + OFF_ZP);
  float* part  = (float*)(ws + OFF_PART);
  bf16*  proj  = (bf16*)(ws + OFF_PROJ);
  bf16*  wtf   = (bf16*)(ws + OFF_WTF2S);
  bf16*  wts   = (bf16*)(ws + OFF_WTS2F);

  hipMemsetAsync(h_ws, 0, 262144, stream);
  hipMemsetAsync(zp, 0, 4096, stream);
  k_means_part<<<dim3(32, 8, 4), 256, 0, stream>>>(f0, f1, f2, f3, part);
  k_means_final<<<dim3(32, 4), 256, 0, stream>>>(part, g);
  k_mlp1<<<dim3(8, 8, 4), 256, 0, stream>>>(g, w1, h_ws);
  k_mlp2<<<8, 256, 0, stream>>>(h_ws, b1, w2, b2, score, cond);
  k_f2s_transpose<<<dim3(1024, 2), 256, 0, stream>>>(f2sw, cond, wtf);
  k_s2f_convert<<<1024, 256, 0, stream>>>(s2fw, wts);
  k_gemms<<<dim3(64, 8, 4), 256, 0, stream>>>(f0, f1, f2, f3, wtf, wts, s2fb,
                                              score, cond, zp, proj, out);
  k_interp<<<dim3(16384, 2), 256, 0, stream>>>(f0, f1, proj, score, cond, out);
}

// Round 3
// 760.679 us; speedup vs baseline: 1.3775x; 1.3775x over previous
//
#include <hip/hip_runtime.h>
#include <math.h>

typedef __bf16 bf16;
typedef bf16 bf16x8 __attribute__((ext_vector_type(8)));
typedef bf16 bf16x4 __attribute__((ext_vector_type(4)));
typedef float f32x4 __attribute__((ext_vector_type(4)));

// ---------------- workspace layout (byte offsets) ----------------
#define OFF_GLOB   0ul          // 4*32*1024 f32      = 524288
#define OFF_H      524288ul     // 8*32*256 f32       = 262144
#define OFF_SCORE  786432ul     // 8*32 f32           = 1024
#define OFF_COND   787456ul     // 8 f32 (+pad)       = 1024
#define OFF_ZP     788480ul     // zero page          = 4096
#define OFF_PART   792576ul     // 4*8*32*1024 f32    = 4194304
#define OFF_PROJ   4986880ul    // 2*128*32*1024 bf16 = 16777216
#define OFF_WTF2S  21764096ul   // 2*5120*1024 bf16   = 20971520
#define OFF_WTS2F  42735616ul   // 1024*1024 bf16     = 2097152
// total ~43 MB (under known-good 62 MB)

// out: out0 @0, out1 @16777216, out2 @33554432, out3 @37748736 (f32 elems)

__device__ __forceinline__ void gll16(const void* gsrc, void* ldst) {
  __builtin_amdgcn_global_load_lds(
      (const __attribute__((address_space(1))) unsigned int*)gsrc,
      (__attribute__((address_space(3))) unsigned int*)ldst, 16, 0, 0);
}

// slot 0..3: slow->fast (2,0)(3,0)(2,1)(3,1) ; slot 4..7: fast->slow (0,2)(1,2)(0,3)(1,3)
__device__ __forceinline__ void slot_ij(int s, int& i, int& j) {
  if (s < 4) { i = 2 + (s & 1); j = s >> 1; }
  else       { int ss = s - 4; i = ss & 1; j = 2 + (ss >> 1); }
}

// ---------------- means ----------------
__global__ __launch_bounds__(256) void k_means_part(
    const float* __restrict__ f0, const float* __restrict__ f1,
    const float* __restrict__ f2, const float* __restrict__ f3,
    float* __restrict__ part)
{
  int b = blockIdx.x, c = blockIdx.y, i = blockIdx.z, tid = threadIdx.x;
  const float* f = (i == 0) ? f0 : (i == 1) ? f1 : (i == 2) ? f2 : f3;
  int chunk = (i < 2) ? 64 : 16;
  int t0 = c * chunk;
  float4 s = make_float4(0.f, 0.f, 0.f, 0.f);
  for (int t = t0; t < t0 + chunk; ++t) {
    float4 v = ((const float4*)(f + (size_t)(t * 32 + b) * 1024))[tid];
    s.x += v.x; s.y += v.y; s.z += v.z; s.w += v.w;
  }
  ((float4*)part)[(size_t)((i * 8 + c) * 32 + b) * 256 + tid] = s;
}

__global__ __launch_bounds__(256) void k_means_final(
    const float* __restrict__ part, float* __restrict__ g)
{
  int b = blockIdx.x, i = blockIdx.y, tid = threadIdx.x;
  float4 s = make_float4(0.f, 0.f, 0.f, 0.f);
  for (int c = 0; c < 8; ++c) {
    float4 v = ((const float4*)part)[(size_t)((i * 8 + c) * 32 + b) * 256 + tid];
    s.x += v.x; s.y += v.y; s.z += v.z; s.w += v.w;
  }
  float inv = (i < 2) ? (1.f / 512.f) : (1.f / 128.f);
  s.x *= inv; s.y *= inv; s.z *= inv; s.w *= inv;
  ((float4*)g)[(size_t)(i * 32 + b) * 256 + tid] = s;
}

// ---------------- MLP layer 1 ----------------
__global__ __launch_bounds__(256) void k_mlp1(
    const float* __restrict__ g, const float* __restrict__ w1, float* __restrict__ h_ws)
{
  int s = blockIdx.x, hc = blockIdx.y, kz = blockIdx.z, tid = threadIdx.x;
  int pi, pj; slot_ij(s, pi, pj);
  int p = pi * 4 + pj;
  int h = hc * 32 + (tid & 31);
  int bg = tid >> 5;
  __shared__ float pv[32 * 65];
  float acc0 = 0.f, acc1 = 0.f, acc2 = 0.f, acc3 = 0.f;
  for (int kt = 0; kt < 8; ++kt) {
    int k0 = kz * 512 + kt * 64;
    __syncthreads();
    for (int l = tid; l < 2048; l += 256) {
      int bb = l >> 6, kk = l & 63;
      int k = k0 + kk;
      float v = (k < 1024) ? g[(size_t)pi * 32768 + bb * 1024 + k]
                           : g[(size_t)pj * 32768 + bb * 1024 + (k - 1024)];
      pv[bb * 65 + kk] = v;
    }
    __syncthreads();
    const float* wp = w1 + ((size_t)p * 2048 + k0) * 256 + hc * 32 + (tid & 31);
    for (int kk = 0; kk < 64; ++kk) {
      float w = wp[(size_t)kk * 256];
      acc0 += pv[(bg * 4 + 0) * 65 + kk] * w;
      acc1 += pv[(bg * 4 + 1) * 65 + kk] * w;
      acc2 += pv[(bg * 4 + 2) * 65 + kk] * w;
      acc3 += pv[(bg * 4 + 3) * 65 + kk] * w;
    }
  }
  atomicAdd(&h_ws[(size_t)s * 8192 + (bg * 4 + 0) * 256 + h], acc0);
  atomicAdd(&h_ws[(size_t)s * 8192 + (bg * 4 + 1) * 256 + h], acc1);
  atomicAdd(&h_ws[(size_t)s * 8192 + (bg * 4 + 2) * 256 + h], acc2);
  atomicAdd(&h_ws[(size_t)s * 8192 + (bg * 4 + 3) * 256 + h], acc3);
}

// ---------------- MLP layer 2 (wave-parallel over batch) ----------------
__global__ __launch_bounds__(256) void k_mlp2(
    const float* __restrict__ h_ws, const float* __restrict__ b1,
    const float* __restrict__ w2, const float* __restrict__ b2,
    float* __restrict__ score, float* __restrict__ cond)
{
  int s = blockIdx.x, tid = threadIdx.x;
  int pi, pj; slot_ij(s, pi, pj);
  int p = pi * 4 + pj;
  int wv = tid >> 6, lane = tid & 63;
  float4 w2v = ((const float4*)(w2 + p * 256))[lane];
  float4 b1v = ((const float4*)(b1 + p * 256))[lane];
  float b2v = b2[p];
  __shared__ float sc_sh[32];
  for (int bb = 0; bb < 8; ++bb) {
    int b = wv * 8 + bb;
    float4 h4 = ((const float4*)(h_ws + (size_t)s * 8192 + b * 256))[lane];
    float v = fmaxf(h4.x + b1v.x, 0.f) * w2v.x + fmaxf(h4.y + b1v.y, 0.f) * w2v.y
            + fmaxf(h4.z + b1v.z, 0.f) * w2v.z + fmaxf(h4.w + b1v.w, 0.f) * w2v.w;
    for (int off = 32; off > 0; off >>= 1) v += __shfl_down(v, off);
    if (lane == 0) {
      float sc = 1.f / (1.f + expf(-(v + b2v)));
      score[s * 32 + b] = sc;
      sc_sh[b] = sc;
    }
  }
  __syncthreads();
  if (tid == 0) {
    float tot = 0.f;
    for (int b = 0; b < 32; ++b) tot += sc_sh[b];
    cond[s] = (tot * (1.f / 32.f) >= 0.3f) ? 1.f : 0.f;
  }
}

// ---------------- f2s weight transpose -> B^T [co][kappa=kk*1024+ci] bf16 ----------------
__global__ __launch_bounds__(256) void k_f2s_transpose(
    const float* __restrict__ w, const float* __restrict__ cond, bf16* __restrict__ wT)
{
  int z = blockIdx.y, co = blockIdx.x, tid = threadIdx.x;
  int sel = (cond[5 + 2 * z] > 0.5f) ? 1 : ((cond[4 + 2 * z] > 0.5f) ? 0 : -1);
  if (sel < 0) return;
  int widx = sel * 2 + z;
  __shared__ float buf[5120];
  const float* src = w + ((size_t)widx * 1024 + co) * 5120;
  for (int l = tid; l < 5120; l += 256) buf[l] = src[l];
  __syncthreads();
  bf16* dst = wT + (size_t)z * 5242880 + (size_t)co * 5120;
  for (int o = tid; o < 5120; o += 256) {
    int kk = o >> 10, ci = o & 1023;
    dst[o] = (bf16)buf[ci * 5 + kk];
  }
}

// ---------------- s2f weight convert ----------------
__global__ __launch_bounds__(256) void k_s2f_convert(
    const float* __restrict__ w, bf16* __restrict__ wT)
{
  size_t gi = (size_t)blockIdx.x * 256 + threadIdx.x;
  float4 v = ((const float4*)w)[gi];
  bf16x4 o;
  o[0] = (bf16)v.x; o[1] = (bf16)v.y; o[2] = (bf16)v.z; o[3] = (bf16)v.w;
  *(bf16x4*)&wT[gi * 4] = o;
}

// ---------------- fused GEMM kernel ----------------
// 512 threads = 2 K-groups x 4 spatial waves. Tile 128x128, BK=64 per kg.
// bz 0,1: f2s (z=bz, K=5120, im2col, epilogue residual->out2/3)
// bz 2,3: s2f (z=bz-2, K=1024, epilogue->proj bf16)
// LDS: As[kg]: [8 chunks][128 rows][8 bf16] 16KB each; Bs[kg]: XOR-swizzled 16KB each.
// Total 64KB; f32 merge buffer (128x128) overlays everything after the K-loop.
__global__ __launch_bounds__(512, 4) void k_fused(
    const float* __restrict__ f0, const float* __restrict__ f1,
    const float* __restrict__ f2, const float* __restrict__ f3,
    const bf16* __restrict__ wtf, const bf16* __restrict__ wts,
    const float* __restrict__ s2fb, const float* __restrict__ score,
    const float* __restrict__ cond, const float* __restrict__ zp,
    bf16* __restrict__ proj, float* __restrict__ out)
{
  __shared__ __align__(16) char smem[65536];
  bf16* AsA = (bf16*)smem;             // 2 x 8192 bf16
  bf16* BsA = (bf16*)(smem + 32768);   // 2 x 8192 bf16
  float* merge = (float*)smem;         // overlay: 128*128 f32 = 65536 B

  int tid = threadIdx.x;
  int kg = tid >> 8, t256 = tid & 255;
  int lane = tid & 63;
  int sp = (tid >> 6) & 3;
  int wr = (sp >> 1) * 64, wc = (sp & 1) * 64;
  int rl = lane & 15, q = lane >> 4;
  int bz = blockIdx.z;
  int N0 = blockIdx.x * 128, M0 = blockIdx.y * 128;  // N fastest: pins B panel per XCD
  int mode = bz >> 1, z = bz & 1;

  bf16* Asb = AsA + kg * 8192;
  bf16* Bsb = BsA + kg * 8192;

  const float* Ag; const bf16* wB; size_t ldb; int KT, kt0, slot = 0;
  const float* fj = nullptr; float* oj = nullptr;

  if (mode == 0) {
    fj = z ? f3 : f2;
    oj = out + 33554432ul + (size_t)z * 4194304;
    int sel = (cond[5 + 2 * z] > 0.5f) ? 1 : ((cond[4 + 2 * z] > 0.5f) ? 0 : -1);
    if (sel < 0) {  // passthrough this 128x128 tile
      for (int l = tid; l < 4096; l += 512) {
        int rr = l >> 5, c = (l & 31) * 4;
        size_t idx = (size_t)(M0 + rr) * 1024 + N0 + c;
        *(float4*)(oj + idx) = *(const float4*)(fj + idx);
      }
      return;
    }
    Ag = sel ? f1 : f0;
    wB = wtf + (size_t)z * 5242880;
    ldb = 5120; KT = 40; kt0 = kg * 40;
    slot = (sel ? 5 : 4) + 2 * z;
  } else {
    int sel = (cond[1 + 2 * z] > 0.5f) ? 3 : ((cond[2 * z] > 0.5f) ? 2 : -1);
    if (sel < 0) return;  // interp does passthrough
    Ag = (sel == 3) ? f3 : f2;
    wB = wts;
    ldb = 1024; KT = 8; kt0 = kg * 8;
  }

  f32x4 acc[4][4];
  #pragma unroll
  for (int a = 0; a < 4; ++a)
    #pragma unroll
    for (int c = 0; c < 4; ++c) { acc[a][c][0] = 0.f; acc[a][c][1] = 0.f; acc[a][c][2] = 0.f; acc[a][c][3] = 0.f; }

  int row = t256 >> 1, half = t256 & 1;      // A staging: 128 rows x 2 halves
  int wg = t256 >> 6, l64 = t256 & 63;       // B staging: wave-in-kg
  int mro = l64 >> 3, csl = l64 & 7, cdat = csl ^ mro;

  for (int ktl = 0; ktl < KT; ++ktl) {
    int kt = kt0 + ktl;
    // ---- A source address (per-row im2col for f2s) ----
    const float* ga;
    if (mode == 0) {
      int kk = kt >> 4, ci0 = (kt & 15) << 6;
      int mm = M0 + row, t = mm >> 5, b = mm & 31;
      int pos = 4 * t - 2 + kk;               // pad=2, stride=4; pos<512 always
      ga = (pos >= 0) ? Ag + (((size_t)(pos * 32 + b)) << 10) + ci0 + half * 32
                      : zp + half * 32;
    } else {
      ga = Ag + (((size_t)(M0 + row)) << 10) + (kt << 6) + half * 32;
    }
    // ---- stage A: f32 -> bf16, [chunk][row] layout (reads 2-way free) ----
    #pragma unroll
    for (int u = 0; u < 4; ++u) {
      float4 v0 = ((const float4*)ga)[2 * u];
      float4 v1 = ((const float4*)ga)[2 * u + 1];
      bf16x8 pk;
      pk[0] = (bf16)v0.x; pk[1] = (bf16)v0.y; pk[2] = (bf16)v0.z; pk[3] = (bf16)v0.w;
      pk[4] = (bf16)v1.x; pk[5] = (bf16)v1.y; pk[6] = (bf16)v1.z; pk[7] = (bf16)v1.w;
      int c = half * 4 + u;
      *(bf16x8*)&Asb[c * 1024 + row * 8] = pk;
    }
    // ---- stage B: async DMA, XOR-swizzled source so frag reads are bank-balanced ----
    #pragma unroll
    for (int u = 0; u < 4; ++u) {
      int br = wg * 32 + u * 8;
      gll16(wB + (size_t)(N0 + br + mro) * ldb + (size_t)kt * 64 + cdat * 8,
            Bsb + br * 64);
    }
    __syncthreads();
    // ---- compute ----
    #pragma unroll
    for (int ks = 0; ks < 2; ++ks) {
      bf16x8 af[4], bfv[4];
      int c = ks * 4 + q;
      #pragma unroll
      for (int mi = 0; mi < 4; ++mi)
        af[mi] = *(const bf16x8*)&Asb[c * 1024 + (wr + mi * 16 + rl) * 8];
      #pragma unroll
      for (int ni = 0; ni < 4; ++ni) {
        int n = wc + ni * 16 + rl;
        int slotb = c ^ (rl & 7);
        bfv[ni] = *(const bf16x8*)&Bsb[n * 64 + slotb * 8];
      }
      #pragma unroll
      for (int mi = 0; mi < 4; ++mi)
        #pragma unroll
        for (int ni = 0; ni < 4; ++ni)
          acc[mi][ni] = __builtin_amdgcn_mfma_f32_16x16x32_bf16(af[mi], bfv[ni], acc[mi][ni], 0, 0, 0);
    }
    __syncthreads();
  }

  // ---- merge K-groups through LDS overlay ----
  if (kg == 1) {
    #pragma unroll
    for (int mi = 0; mi < 4; ++mi)
      #pragma unroll
      for (int ni = 0; ni < 4; ++ni)
        #pragma unroll
        for (int r = 0; r < 4; ++r)
          merge[(wr + mi * 16 + q * 4 + r) * 128 + wc + ni * 16 + rl] = acc[mi][ni][r];
  }
  __syncthreads();
  if (kg == 0) {
    if (mode == 0) {
      #pragma unroll
      for (int mi = 0; mi < 4; ++mi)
        #pragma unroll
        for (int ni = 0; ni < 4; ++ni) {
          int gm = M0 + wr + mi * 16 + q * 4;
          int gn = N0 + wc + ni * 16 + rl;
          #pragma unroll
          for (int r = 0; r < 4; ++r) {
            float sum = acc[mi][ni][r] + merge[(wr + mi * 16 + q * 4 + r) * 128 + wc + ni * 16 + rl];
            size_t idx = (size_t)(gm + r) * 1024 + gn;
            oj[idx] = fj[idx] + score[slot * 32 + ((gm + r) & 31)] * sum;
          }
        }
    } else {
      bf16* pj = proj + (size_t)z * 4194304;
      #pragma unroll
      for (int mi = 0; mi < 4; ++mi)
        #pragma unroll
        for (int ni = 0; ni < 4; ++ni) {
          int gm = M0 + wr + mi * 16 + q * 4;
          int gn = N0 + wc + ni * 16 + rl;
          float bv = s2fb[gn];
          #pragma unroll
          for (int r = 0; r < 4; ++r) {
            float sum = acc[mi][ni][r] + merge[(wr + mi * 16 + q * 4 + r) * 128 + wc + ni * 16 + rl];
            pj[(size_t)(gm + r) * 1024 + gn] = (bf16)(sum + bv);
          }
        }
    }
  }
}

// ---------------- interp + residual -> out0/out1 ----------------
__global__ __launch_bounds__(256) void k_interp(
    const float* __restrict__ f0, const float* __restrict__ f1,
    const bf16* __restrict__ proj, const float* __restrict__ score,
    const float* __restrict__ cond, float* __restrict__ out)
{
  int z = blockIdx.y, tb = blockIdx.x, tid = threadIdx.x;
  const float* fj = z ? f1 : f0;
  float* oj = out + (size_t)z * 16777216;
  int sel = (cond[1 + 2 * z] > 0.5f) ? 3 : ((cond[2 * z] > 0.5f) ? 2 : -1);
  float4 fv = ((const float4*)(fj + (size_t)tb * 1024))[tid];
  if (sel < 0) {
    ((float4*)(oj + (size_t)tb * 1024))[tid] = fv;
    return;
  }
  int t = tb >> 5, b = tb & 31;
  int slot = 2 * z + (sel == 3 ? 1 : 0);
  float s = score[slot * 32 + b];
  float srcf = 0.25f * (float)t - 0.375f;
  srcf = fminf(fmaxf(srcf, 0.f), 127.f);
  int i0 = (int)srcf;
  int i1 = min(i0 + 1, 127);
  float w = srcf - (float)i0;
  const bf16* pz = proj + (size_t)z * 4194304;
  bf16x4 a4 = *(const bf16x4*)&pz[((size_t)(i0 * 32 + b)) * 1024 + tid * 4];
  bf16x4 c4 = *(const bf16x4*)&pz[((size_t)(i1 * 32 + b)) * 1024 + tid * 4];
  float4 o;
  o.x = fv.x + s * ((1.f - w) * (float)a4[0] + w * (float)c4[0]);
  o.y = fv.y + s * ((1.f - w) * (float)a4[1] + w * (float)c4[1]);
  o.z = fv.z + s * ((1.f - w) * (float)a4[2] + w * (float)c4[2]);
  o.w = fv.w + s * ((1.f - w) * (float)a4[3] + w * (float)c4[3]);
  ((float4*)(oj + (size_t)tb * 1024))[tid] = o;
}

// ---------------- launch ----------------
extern "C" void kernel_launch(void* const* d_in, const int* in_sizes, int n_in,
                              void* d_out, int out_size, void* d_ws, size_t ws_size,
                              hipStream_t stream) {
  const float* f0   = (const float*)d_in[0];
  const float* f1   = (const float*)d_in[1];
  const float* f2   = (const float*)d_in[2];
  const float* f3   = (const float*)d_in[3];
  const float* w1   = (const float*)d_in[4];
  const float* b1   = (const float*)d_in[5];
  const float* w2   = (const float*)d_in[6];
  const float* b2   = (const float*)d_in[7];
  const float* s2fw = (const float*)d_in[8];
  const float* s2fb = (const float*)d_in[9];
  const float* f2sw = (const float*)d_in[10];
  float* out = (float*)d_out;

  char* ws = (char*)d_ws;
  float* g     = (float*)(ws + OFF_GLOB);
  float* h_ws  = (float*)(ws + OFF_H);
  float* score = (float*)(ws + OFF_SCORE);
  float* cond  = (float*)(ws + OFF_COND);
  float* zp    = (float*)(ws + OFF_ZP);
  float* part  = (float*)(ws + OFF_PART);
  bf16*  proj  = (bf16*)(ws + OFF_PROJ);
  bf16*  wtf   = (bf16*)(ws + OFF_WTF2S);
  bf16*  wts   = (bf16*)(ws + OFF_WTS2F);

  hipMemsetAsync(h_ws, 0, 262144, stream);
  hipMemsetAsync(zp, 0, 4096, stream);
  k_means_part<<<dim3(32, 8, 4), 256, 0, stream>>>(f0, f1, f2, f3, part);
  k_means_final<<<dim3(32, 4), 256, 0, stream>>>(part, g);
  k_mlp1<<<dim3(8, 8, 4), 256, 0, stream>>>(g, w1, h_ws);
  k_mlp2<<<8, 256, 0, stream>>>(h_ws, b1, w2, b2, score, cond);
  k_f2s_transpose<<<dim3(1024, 2), 256, 0, stream>>>(f2sw, cond, wtf);
  k_s2f_convert<<<1024, 256, 0, stream>>>(s2fw, wts);
  k_fused<<<dim3(8, 32, 4), 512, 0, stream>>>(f0, f1, f2, f3, wtf, wts, s2fb,
                                              score, cond, zp, proj, out);
  k_interp<<<dim3(16384, 2), 256, 0, stream>>>(f0, f1, proj, score, cond, out);
}